// Round 9
// baseline (5507.921 us; speedup 1.0000x reference)
//
#include <hip/hip_runtime.h>
#include <stdint.h>

#define L_SEQ 2048
#define NB 2
#define EMB 1024
#define NH 16
#define DH 64
#define NC 32
#define MROWS 4096  // L*NB

// Naive tiled f32 GEMM: C[M,1024] = A[M,1024] @ B^T + bias, B[1024,1024] row j = output col j.
// 64x64 tile, BK=32, 256 threads, each thread 4x4 outputs. Pure f32 (FMA accum).
__global__ void __launch_bounds__(256) gemm_f32_bt(
    const float* __restrict__ A, const float* __restrict__ B,
    const float* __restrict__ bias, float* __restrict__ C)
{
  __shared__ float As[64][33];
  __shared__ float Bs[64][33];
  int tid = threadIdx.x, tx = tid & 15, ty = tid >> 4;
  int m0 = blockIdx.y * 64, n0 = blockIdx.x * 64;
  float acc[4][4] = {};

  for (int k0 = 0; k0 < EMB; k0 += 32) {
    __syncthreads();
#pragma unroll
    for (int i = 0; i < 8; i++) {
      int e = tid + i * 256;        // 2048 elems per tile
      int r = e >> 5, c = e & 31;
      As[r][c] = A[(size_t)(m0 + r) * EMB + k0 + c];
      Bs[r][c] = B[(size_t)(n0 + r) * EMB + k0 + c];
    }
    __syncthreads();
#pragma unroll 8
    for (int kk = 0; kk < 32; kk++) {
      float a0 = As[ty * 4 + 0][kk], a1 = As[ty * 4 + 1][kk];
      float a2 = As[ty * 4 + 2][kk], a3 = As[ty * 4 + 3][kk];
      float b0 = Bs[tx * 4 + 0][kk], b1 = Bs[tx * 4 + 1][kk];
      float b2 = Bs[tx * 4 + 2][kk], b3 = Bs[tx * 4 + 3][kk];
      acc[0][0] += a0 * b0; acc[0][1] += a0 * b1; acc[0][2] += a0 * b2; acc[0][3] += a0 * b3;
      acc[1][0] += a1 * b0; acc[1][1] += a1 * b1; acc[1][2] += a1 * b2; acc[1][3] += a1 * b3;
      acc[2][0] += a2 * b0; acc[2][1] += a2 * b1; acc[2][2] += a2 * b2; acc[2][3] += a2 * b3;
      acc[3][0] += a3 * b0; acc[3][1] += a3 * b1; acc[3][2] += a3 * b2; acc[3][3] += a3 * b3;
    }
  }
#pragma unroll
  for (int i = 0; i < 4; i++)
#pragma unroll
    for (int j = 0; j < 4; j++) {
      int row = m0 + ty * 4 + i, col = n0 + tx * 4 + j;
      C[(size_t)row * EMB + col] = acc[i][j] + bias[col];
    }
}

// Spherical k-means assignment on projected f32 rows (mirrors _assign):
// argmax_c X[row]·cent[c] (row norm is a positive scalar -> argmax invariant).
// f64 accumulation, first-max tie-break.
__global__ void __launch_bounds__(256) assign_cos(
    const float* __restrict__ X, const float* __restrict__ cent, int* __restrict__ cluster)
{
  int row = blockIdx.x;
  int tid = threadIdx.x, wave = tid >> 6, lane = tid & 63;
  float4 x = *(const float4*)(X + (size_t)row * EMB + tid * 4);
  __shared__ double wsum[4][NC];
  __shared__ double dots[NC];
  for (int c = 0; c < NC; c++) {
    float4 cv = *(const float4*)(cent + (size_t)c * EMB + tid * 4);
    double p = (double)x.x * cv.x + (double)x.y * cv.y + (double)x.z * cv.z + (double)x.w * cv.w;
#pragma unroll
    for (int off = 32; off; off >>= 1) p += __shfl_xor(p, off, 64);
    if (lane == 0) wsum[wave][c] = p;
  }
  __syncthreads();
  if (tid < NC) dots[tid] = wsum[0][tid] + wsum[1][tid] + wsum[2][tid] + wsum[3][tid];
  __syncthreads();
  if (tid == 0) {
    double best = dots[0]; int bc = 0;
    for (int c = 1; c < NC; c++) if (dots[c] > best) { best = dots[c]; bc = c; }  // first-max
    cluster[row] = bc;
  }
}

// Dense masked attention, pure f32. Block = (4 queries, head, batch); wave-per-query.
// Rows of Qf/Kf/Vf are (L,N,E)-flat: row = seq*NB + n.
__global__ void __launch_bounds__(256) attn_dense(
    const float* __restrict__ Qf, const float* __restrict__ Kf, const float* __restrict__ Vf,
    const int* __restrict__ qcl, const int* __restrict__ kcl, float* __restrict__ ctx)
{
  int h = blockIdx.y, n = blockIdx.z;
  int wave = threadIdx.x >> 6, lane = threadIdx.x & 63;
  int l = blockIdx.x * 4 + wave;
  __shared__ float sbuf[4][L_SEQ];

  int qc = qcl[l * NB + n];
  float qd = Qf[(size_t)(l * NB + n) * EMB + h * DH + lane];  // lane = d
  float m = -3.0e38f;

  for (int j0 = 0; j0 < L_SEQ; j0 += 64) {
    int j = j0 + lane;  // key index
    const float4* kr4 = (const float4*)(Kf + (size_t)(j * NB + n) * EMB + h * DH);
    float accd = 0.f;
#pragma unroll
    for (int d4 = 0; d4 < 16; d4++) {
      float4 kv = kr4[d4];
      accd += __shfl(qd, d4 * 4 + 0, 64) * kv.x;
      accd += __shfl(qd, d4 * 4 + 1, 64) * kv.y;
      accd += __shfl(qd, d4 * 4 + 2, 64) * kv.z;
      accd += __shfl(qd, d4 * 4 + 3, 64) * kv.w;
    }
    bool match = (kcl[j * NB + n] == qc);
    float sc = match ? accd * 0.125f : -3.0e38f;   // 1/sqrt(64)
    sbuf[wave][j] = sc;
    m = fmaxf(m, sc);
  }
#pragma unroll
  for (int off = 32; off; off >>= 1) m = fmaxf(m, __shfl_xor(m, off, 64));
  __syncthreads();

  float acc = 0.f;
  if (m > -1.0e37f) {            // wave-uniform
    float lsum = 0.f;
    for (int j = 0; j < L_SEQ; j++) {
      float sv = sbuf[wave][j];  // uniform broadcast
      if (sv > -1.0e37f) {
        float p = __expf(sv - m);
        lsum += p;
        acc += p * Vf[(size_t)(j * NB + n) * EMB + h * DH + lane];
      }
    }
    acc /= lsum;
  }
  ctx[(size_t)(n * L_SEQ + l) * EMB + h * DH + lane] = acc;   // internal ctx row = n*L+l
}

// Residual + LayerNorm. OUTPUT IS FLOAT32 (reference output dtype) — row = l*NB+n.
__global__ void __launch_bounds__(256) ln_kernel(
    const float* __restrict__ proj, const float* __restrict__ query,
    const float* __restrict__ gamma, const float* __restrict__ beta,
    float* __restrict__ out)
{
  int r = blockIdx.x;          // r = l*NB + n  (output/query row, (L,N,E)-flat)
  int l = r >> 1, n = r & 1;
  int tid = threadIdx.x, wave = tid >> 6, lane = tid & 63;
  float4 p = *(const float4*)(proj + ((size_t)(n * L_SEQ + l)) * EMB + tid * 4);
  float4 qu = *(const float4*)(query + (size_t)r * EMB + tid * 4);
  float res[4] = { p.x + qu.x, p.y + qu.y, p.z + qu.z, p.w + qu.w };
  float s1 = res[0] + res[1] + res[2] + res[3];
  float s2 = res[0] * res[0] + res[1] * res[1] + res[2] * res[2] + res[3] * res[3];
#pragma unroll
  for (int off = 32; off; off >>= 1) {
    s1 += __shfl_xor(s1, off, 64);
    s2 += __shfl_xor(s2, off, 64);
  }
  __shared__ float a1[4], a2[4];
  if (lane == 0) { a1[wave] = s1; a2[wave] = s2; }
  __syncthreads();
  float t1 = a1[0] + a1[1] + a1[2] + a1[3];
  float t2 = a2[0] + a2[1] + a2[2] + a2[3];
  float mu = t1 * (1.f / EMB);
  float var = fmaxf(t2 * (1.f / EMB) - mu * mu, 0.f);
  float rstd = 1.f / sqrtf(var + 1e-5f);
  float4 gu = *(const float4*)(gamma + tid * 4);
  float4 bu = *(const float4*)(beta + tid * 4);
  float4 o;
  o.x = (res[0] - mu) * rstd * gu.x + bu.x;
  o.y = (res[1] - mu) * rstd * gu.y + bu.y;
  o.z = (res[2] - mu) * rstd * gu.z + bu.z;
  o.w = (res[3] - mu) * rstd * gu.w + bu.w;
  *(float4*)(out + (size_t)r * EMB + tid * 4) = o;
}

extern "C" void kernel_launch(void* const* d_in, const int* in_sizes, int n_in,
                              void* d_out, int out_size, void* d_ws, size_t ws_size,
                              hipStream_t stream) {
  const float* query = (const float*)d_in[0];
  const float* key   = (const float*)d_in[1];
  const float* value = (const float*)d_in[2];
  const float* Wq = (const float*)d_in[3];
  const float* bq = (const float*)d_in[4];
  const float* Wk = (const float*)d_in[5];
  const float* bk = (const float*)d_in[6];
  const float* Wv = (const float*)d_in[7];
  const float* bv = (const float*)d_in[8];
  const float* Wo = (const float*)d_in[9];
  const float* bo = (const float*)d_in[10];
  const float* cq = (const float*)d_in[11];
  const float* ck = (const float*)d_in[12];
  const float* gamma = (const float*)d_in[13];
  const float* beta  = (const float*)d_in[14];
  float* out = (float*)d_out;   // reference output dtype = float32

  const size_t MB_EL = (size_t)MROWS * EMB;   // 4M elements

  // workspace: 4 x 16 MB f32 + 32 KB ≈ 64 MB
  float* Qf  = (float*)d_ws;        // [4096,1024], row = seq*2+n
  float* Kf  = Qf + MB_EL;
  float* Vf  = Kf + MB_EL;
  float* ctx = Vf + MB_EL;          // row = n*L+l
  int* q_cluster = (int*)(ctx + MB_EL);
  int* k_cluster = q_cluster + MROWS;
  float* proj = Qf;                 // alias: Qf dead after attention

  dim3 gg(EMB / 64, MROWS / 64);
  gemm_f32_bt<<<gg, 256, 0, stream>>>(query, Wq, bq, Qf);
  gemm_f32_bt<<<gg, 256, 0, stream>>>(key,   Wk, bk, Kf);
  gemm_f32_bt<<<gg, 256, 0, stream>>>(value, Wv, bv, Vf);

  assign_cos<<<MROWS, 256, 0, stream>>>(Qf, cq, q_cluster);
  assign_cos<<<MROWS, 256, 0, stream>>>(Kf, ck, k_cluster);

  attn_dense<<<dim3(L_SEQ / 4, NH, NB), 256, 0, stream>>>(Qf, Kf, Vf, q_cluster, k_cluster, ctx);

  gemm_f32_bt<<<gg, 256, 0, stream>>>(ctx, Wo, bo, proj);
  ln_kernel<<<MROWS, 256, 0, stream>>>(proj, query, gamma, beta, out);
}

// Round 10
// 727.584 us; speedup vs baseline: 7.5702x; 7.5702x over previous
//
#include <hip/hip_runtime.h>
#include <stdint.h>

#define L_SEQ 2048
#define S_SEQ 2048
#define NB 2
#define EMB 1024
#define NH 16
#define DH 64
#define NC 32
#define MROWS 4096  // L*NB

typedef __bf16 bf16x8 __attribute__((ext_vector_type(8)));
typedef float f32x4 __attribute__((ext_vector_type(4)));

__device__ __forceinline__ float bf2f(unsigned short u) {
  return __builtin_bit_cast(float, (uint32_t)u << 16);
}
__device__ __forceinline__ unsigned short f2bf(float f) {
  uint32_t u = __builtin_bit_cast(uint32_t, f);
  return (unsigned short)((u + 0x7FFFu + ((u >> 16) & 1u)) >> 16);
}

// C = A @ B^T + bias. MFMA bf16, 128x128 tile (m93/m97-validated structure).
// A_BF16: 0 = A is f32 global (inline RNE convert), 1 = A is bf16 workspace.
// B always f32 global (inline convert). Out: f32 if outF, else bf16 outB.
template <int A_BF16>
__global__ void __launch_bounds__(256) gemm_bt_mfma(
    const void* __restrict__ Av, const float* __restrict__ B,
    const float* __restrict__ bias,
    float* __restrict__ outF, unsigned short* __restrict__ outB)
{
  __shared__ __align__(16) unsigned short As[128][32];  // unpadded 64B rows (b128-aligned)
  __shared__ __align__(16) unsigned short Bs[128][32];
  const int K = EMB;
  int tid = threadIdx.x;
  int m0 = blockIdx.y * 128, n0 = blockIdx.x * 128;
  int wave = tid >> 6, lane = tid & 63;
  int wm = (wave >> 1) * 64, wn = (wave & 1) * 64;

  f32x4 zero = {0.f, 0.f, 0.f, 0.f};
  f32x4 acc[4][4];
#pragma unroll
  for (int mi = 0; mi < 4; mi++)
#pragma unroll
    for (int ni = 0; ni < 4; ni++) acc[mi][ni] = zero;

  int fr = lane & 15, fk = (lane >> 4) * 8;

  for (int k0 = 0; k0 < K; k0 += 32) {
    __syncthreads();
#pragma unroll
    for (int it = 0; it < 2; it++) {
      int ch = tid + it * 256;          // 512 chunks of 8 elems per tile
      int row = ch >> 2, kk = (ch & 3) * 8;
      if (A_BF16) {
        const unsigned short* ap = (const unsigned short*)Av + (size_t)(m0 + row) * K + k0 + kk;
        *(uint4*)(&As[row][kk]) = *(const uint4*)ap;
      } else {
        const float* ap = (const float*)Av + (size_t)(m0 + row) * K + k0 + kk;
        float4 a0 = *(const float4*)ap, a1 = *(const float4*)(ap + 4);
        uint4 u;
        u.x = (uint32_t)f2bf(a0.x) | ((uint32_t)f2bf(a0.y) << 16);
        u.y = (uint32_t)f2bf(a0.z) | ((uint32_t)f2bf(a0.w) << 16);
        u.z = (uint32_t)f2bf(a1.x) | ((uint32_t)f2bf(a1.y) << 16);
        u.w = (uint32_t)f2bf(a1.z) | ((uint32_t)f2bf(a1.w) << 16);
        *(uint4*)(&As[row][kk]) = u;
      }
      {
        const float* bp = B + (size_t)(n0 + row) * K + k0 + kk;
        float4 b0 = *(const float4*)bp, b1 = *(const float4*)(bp + 4);
        uint4 u;
        u.x = (uint32_t)f2bf(b0.x) | ((uint32_t)f2bf(b0.y) << 16);
        u.y = (uint32_t)f2bf(b0.z) | ((uint32_t)f2bf(b0.w) << 16);
        u.z = (uint32_t)f2bf(b1.x) | ((uint32_t)f2bf(b1.y) << 16);
        u.w = (uint32_t)f2bf(b1.z) | ((uint32_t)f2bf(b1.w) << 16);
        *(uint4*)(&Bs[row][kk]) = u;
      }
    }
    __syncthreads();
    bf16x8 af[4], bfr[4];
#pragma unroll
    for (int i = 0; i < 4; i++) af[i] = *(const bf16x8*)(&As[wm + i * 16 + fr][fk]);
#pragma unroll
    for (int i = 0; i < 4; i++) bfr[i] = *(const bf16x8*)(&Bs[wn + i * 16 + fr][fk]);
#pragma unroll
    for (int mi = 0; mi < 4; mi++)
#pragma unroll
      for (int ni = 0; ni < 4; ni++)
        acc[mi][ni] = __builtin_amdgcn_mfma_f32_16x16x32_bf16(af[mi], bfr[ni], acc[mi][ni], 0, 0, 0);
  }

#pragma unroll
  for (int ni = 0; ni < 4; ni++) {
    int col = n0 + wn + ni * 16 + (lane & 15);
    float bv = bias[col];
#pragma unroll
    for (int mi = 0; mi < 4; mi++) {
#pragma unroll
      for (int r = 0; r < 4; r++) {
        int row = m0 + wm + mi * 16 + (lane >> 4) * 4 + r;
        float v = acc[mi][ni][r] + bv;
        if (outF) outF[(size_t)row * EMB + col] = v;
        else outB[(size_t)row * EMB + col] = f2bf(v);
      }
    }
  }
}

// Wc[c][k] = sum_e W[e][k]*cent[c][e]; bd[c] = sum_e bias[e]*cent[c][e]; f64 (exact reassociation:
// (x@W^T+b)·cent_c = sum_k x_k*Wc[c][k] + bd[c]). Inputs f32.
__global__ void __launch_bounds__(256) prep_wc_kernel(
    const float* __restrict__ W, const float* __restrict__ bias,
    const float* __restrict__ cent,
    double* __restrict__ Wc, double* __restrict__ bd)
{
  int k = blockIdx.x;
  int tid = threadIdx.x;
  int c = tid & 31, g = tid >> 5;
  __shared__ double red[8][32];
  double s = 0.0;
  for (int e = g * 128; e < (g + 1) * 128; e++)
    s += (double)W[(size_t)e * EMB + k] * (double)cent[(size_t)c * EMB + e];
  red[g][c] = s;
  __syncthreads();
  if (tid < 32) {
    double t = 0.0;
#pragma unroll
    for (int gg = 0; gg < 8; gg++) t += red[gg][tid];
    Wc[(size_t)tid * EMB + k] = t;
  }
  if (k == 0) {
    __syncthreads();
    double s2 = 0.0;
    for (int e = g * 128; e < (g + 1) * 128; e++)
      s2 += (double)bias[e] * (double)cent[(size_t)c * EMB + e];
    red[g][c] = s2;
    __syncthreads();
    if (tid < 32) {
      double t = 0.0;
#pragma unroll
      for (int gg = 0; gg < 8; gg++) t += red[gg][tid];
      bd[tid] = t;
    }
  }
}

// Assignment from RAW f32 input rows via Wc: f64 dots, first-max argmax. (Bit-agreed with
// projected-cosine assignment in R3-R6 cross-validation.)
__global__ void __launch_bounds__(256) assign2_kernel(
    const float* __restrict__ X, const double* __restrict__ Wc,
    const double* __restrict__ bd,
    int* __restrict__ cluster, int* __restrict__ count)
{
  int r0 = blockIdx.x * 4;
  int tid = threadIdx.x;
  int c = tid & 31, seg = tid >> 5;
  __shared__ double red[4][32][8];
  __shared__ double dots[4][32];

  const double* wp = Wc + (size_t)c * EMB + seg * 128;
  double acc4[4] = {0.0, 0.0, 0.0, 0.0};
  for (int i = 0; i < 128; i += 2) {
    double2 w2 = *(const double2*)(wp + i);
#pragma unroll
    for (int r = 0; r < 4; r++) {
      float2 xu = *(const float2*)(X + (size_t)(r0 + r) * EMB + seg * 128 + i);
      acc4[r] += (double)xu.x * w2.x + (double)xu.y * w2.y;
    }
  }
#pragma unroll
  for (int r = 0; r < 4; r++) red[r][c][seg] = acc4[r];
  __syncthreads();
  if (tid < 128) {
    int r = tid >> 5, cc = tid & 31;
    double t = 0.0;
#pragma unroll
    for (int s = 0; s < 8; s++) t += red[r][cc][s];
    dots[r][cc] = t + bd[cc];
  }
  __syncthreads();
  if (tid < 4) {
    double best = dots[tid][0]; int bc = 0;
    for (int cc = 1; cc < NC; cc++)
      if (dots[tid][cc] > best) { best = dots[tid][cc]; bc = cc; }   // first-max
    int row = r0 + tid;
    cluster[row] = bc;
    atomicAdd(&count[(row & 1) * NC + bc], 1);
  }
}

__global__ void scan_kernel(const int* __restrict__ qcount, const int* __restrict__ kcount,
                            int* __restrict__ qoff, int* __restrict__ koff)
{
  int tid = threadIdx.x;
  if (tid < 2) {
    int run = 0;
    for (int c = 0; c < NC; c++) { qoff[tid * NC + c] = run; run += qcount[tid * NC + c]; }
  } else if (tid < 4) {
    int n = tid - 2, run = 0;
    for (int c = 0; c < NC; c++) { koff[n * NC + c] = run; run += kcount[n * NC + c]; }
  }
}

__global__ void __launch_bounds__(256) scatter_kernel(
    const int* __restrict__ q_cluster, const int* __restrict__ k_cluster,
    const int* __restrict__ qoff, const int* __restrict__ koff,
    int* __restrict__ qfill, int* __restrict__ kfill,
    int* __restrict__ qlist, int* __restrict__ klist)
{
  int id = blockIdx.x * 256 + threadIdx.x;
  if (id < MROWS) {
    int row = id, n = row & 1, l = row >> 1, c = q_cluster[row];
    int pos = atomicAdd(&qfill[n * NC + c], 1);
    qlist[n * L_SEQ + qoff[n * NC + c] + pos] = l;
  } else {
    int row = id - MROWS, n = row & 1, s = row >> 1, c = k_cluster[row];
    int pos = atomicAdd(&kfill[n * NC + c], 1);
    klist[n * S_SEQ + koff[n * NC + c] + pos] = s;
  }
}

// Bucketed attention: block = (cluster, head, batch); wave-per-query. Q/K/V bf16, f32 math.
// Q/K/V rows are (L,N,E)-flat: row = seq*NB+n. ctx row = n*L+l.
__global__ void __launch_bounds__(256) attn_bucket(
    const unsigned short* __restrict__ Qb, const unsigned short* __restrict__ Kb,
    const unsigned short* __restrict__ Vb,
    const int* __restrict__ qcount, const int* __restrict__ qoff, const int* __restrict__ qlist,
    const int* __restrict__ kcount, const int* __restrict__ koff, const int* __restrict__ klist,
    unsigned short* __restrict__ ctx)
{
  int c = blockIdx.x, h = blockIdx.y, n = blockIdx.z;
  int Sc = kcount[n * NC + c], k0 = koff[n * NC + c];
  int Lc = qcount[n * NC + c], q0 = qoff[n * NC + c];
  __shared__ float sbuf[4][S_SEQ];
  int wave = threadIdx.x >> 6, lane = threadIdx.x & 63;

  if (Sc == 0) {   // no keys: ref softmax would be NaN; R9 proved this never occurs. Write 0.
    for (int qi = wave; qi < Lc; qi += 4) {
      int l = qlist[n * L_SEQ + q0 + qi];
      ctx[((size_t)(n * L_SEQ + l)) * EMB + h * DH + lane] = 0;
    }
    return;
  }

  const int* kl = klist + n * S_SEQ + k0;

  for (int qi = wave; qi < Lc; qi += 4) {
    int l = qlist[n * L_SEQ + q0 + qi];
    float qd = bf2f(Qb[((size_t)(l * NB + n)) * EMB + h * DH + lane]);   // lane = d
    float m = -3.0e38f;
    for (int j0 = 0; j0 < Sc; j0 += 64) {   // pass 1: lane = key
      int j = j0 + lane;
      int jc = j < Sc ? j : Sc - 1;         // clamp: keep lanes active for shfl
      int s = kl[jc];
      const ushort4* kr4 = (const ushort4*)(Kb + ((size_t)(s * NB + n)) * EMB + h * DH);
      float accd = 0.f;
#pragma unroll
      for (int d4 = 0; d4 < 16; d4++) {
        ushort4 ku = kr4[d4];
        accd += __shfl(qd, d4 * 4 + 0, 64) * bf2f(ku.x);
        accd += __shfl(qd, d4 * 4 + 1, 64) * bf2f(ku.y);
        accd += __shfl(qd, d4 * 4 + 2, 64) * bf2f(ku.z);
        accd += __shfl(qd, d4 * 4 + 3, 64) * bf2f(ku.w);
      }
      float sc = accd * 0.125f;             // 1/sqrt(64)
      if (j < Sc) { sbuf[wave][j] = sc; m = fmaxf(m, sc); }
    }
#pragma unroll
    for (int off = 32; off; off >>= 1) m = fmaxf(m, __shfl_xor(m, off, 64));
    float lsum = 0.f, acc = 0.f;            // pass 2: lane = d
    for (int j = 0; j < Sc; j++) {
      float p = __expf(sbuf[wave][j] - m);
      int s = kl[j];
      float vv = bf2f(Vb[((size_t)(s * NB + n)) * EMB + h * DH + lane]);
      lsum += p;
      acc += p * vv;
    }
    ctx[((size_t)(n * L_SEQ + l)) * EMB + h * DH + lane] = f2bf(acc / lsum);
  }
}

// Residual + LayerNorm, f32 output. out row r = l*NB+n; proj row = n*L+l. (R9-validated.)
__global__ void __launch_bounds__(256) ln_kernel(
    const float* __restrict__ proj, const float* __restrict__ query,
    const float* __restrict__ gamma, const float* __restrict__ beta,
    float* __restrict__ out)
{
  int r = blockIdx.x;
  int l = r >> 1, n = r & 1;
  int tid = threadIdx.x, wave = tid >> 6, lane = tid & 63;
  float4 p = *(const float4*)(proj + ((size_t)(n * L_SEQ + l)) * EMB + tid * 4);
  float4 qu = *(const float4*)(query + (size_t)r * EMB + tid * 4);
  float res[4] = { p.x + qu.x, p.y + qu.y, p.z + qu.z, p.w + qu.w };
  float s1 = res[0] + res[1] + res[2] + res[3];
  float s2 = res[0] * res[0] + res[1] * res[1] + res[2] * res[2] + res[3] * res[3];
#pragma unroll
  for (int off = 32; off; off >>= 1) {
    s1 += __shfl_xor(s1, off, 64);
    s2 += __shfl_xor(s2, off, 64);
  }
  __shared__ float a1[4], a2[4];
  if (lane == 0) { a1[wave] = s1; a2[wave] = s2; }
  __syncthreads();
  float t1 = a1[0] + a1[1] + a1[2] + a1[3];
  float t2 = a2[0] + a2[1] + a2[2] + a2[3];
  float mu = t1 * (1.f / EMB);
  float var = fmaxf(t2 * (1.f / EMB) - mu * mu, 0.f);
  float rstd = 1.f / sqrtf(var + 1e-5f);
  float4 gu = *(const float4*)(gamma + tid * 4);
  float4 bu = *(const float4*)(beta + tid * 4);
  float4 o;
  o.x = (res[0] - mu) * rstd * gu.x + bu.x;
  o.y = (res[1] - mu) * rstd * gu.y + bu.y;
  o.z = (res[2] - mu) * rstd * gu.z + bu.z;
  o.w = (res[3] - mu) * rstd * gu.w + bu.w;
  *(float4*)(out + (size_t)r * EMB + tid * 4) = o;
}

extern "C" void kernel_launch(void* const* d_in, const int* in_sizes, int n_in,
                              void* d_out, int out_size, void* d_ws, size_t ws_size,
                              hipStream_t stream) {
  const float* query = (const float*)d_in[0];
  const float* key   = (const float*)d_in[1];
  const float* value = (const float*)d_in[2];
  const float* Wq = (const float*)d_in[3];
  const float* bq = (const float*)d_in[4];
  const float* Wk = (const float*)d_in[5];
  const float* bk = (const float*)d_in[6];
  const float* Wv = (const float*)d_in[7];
  const float* bv = (const float*)d_in[8];
  const float* Wo = (const float*)d_in[9];
  const float* bo = (const float*)d_in[10];
  const float* cq = (const float*)d_in[11];
  const float* ck = (const float*)d_in[12];
  const float* gamma = (const float*)d_in[13];
  const float* beta  = (const float*)d_in[14];
  float* out = (float*)d_out;   // f32 output (reference dtype)

  const size_t MB_EL = (size_t)MROWS * EMB;   // 4M elements

  // workspace (~33 MB): control block first, then bf16 tensors; proj aliases Qb+Kb.
  int* q_cluster = (int*)d_ws;               // 16 KB
  int* k_cluster = q_cluster + MROWS;        // 16 KB
  int* qcount = k_cluster + MROWS;           // 6 x 64 ints contiguous (one memset)
  int* kcount = qcount + 64;
  int* qoff   = kcount + 64;
  int* koff   = qoff + 64;
  int* qfill  = koff + 64;
  int* kfill  = qfill + 64;
  int* qlist  = kfill + 64;                  // [2][2048]
  int* klist  = qlist + MROWS;               // [2][2048]
  double* Wcq = (double*)(klist + MROWS);    // 256 KB (offset 67072, 16B-aligned)
  double* Wck = Wcq + (size_t)NC * EMB;      // 256 KB
  double* bdq = Wck + (size_t)NC * EMB;
  double* bdk = bdq + NC;
  unsigned short* Qb  = (unsigned short*)(bdk + NC);  // 8 MB bf16, row = seq*2+n
  unsigned short* Kb  = Qb + MB_EL;                   // 8 MB
  unsigned short* Vb  = Kb + MB_EL;                   // 8 MB
  unsigned short* ctx = Vb + MB_EL;                   // 8 MB, row = n*L+l
  float* proj = (float*)Qb;    // 16 MB f32 overlays Qb+Kb (dead after attention)

  hipMemsetAsync(qcount, 0, 6 * 64 * sizeof(int), stream);

  prep_wc_kernel<<<EMB, 256, 0, stream>>>(Wq, bq, cq, Wcq, bdq);
  prep_wc_kernel<<<EMB, 256, 0, stream>>>(Wk, bk, ck, Wck, bdk);

  dim3 gg(EMB / 128, MROWS / 128);
  gemm_bt_mfma<0><<<gg, 256, 0, stream>>>(query, Wq, bq, nullptr, Qb);
  gemm_bt_mfma<0><<<gg, 256, 0, stream>>>(key,   Wk, bk, nullptr, Kb);
  gemm_bt_mfma<0><<<gg, 256, 0, stream>>>(value, Wv, bv, nullptr, Vb);

  assign2_kernel<<<MROWS / 4, 256, 0, stream>>>(query, Wcq, bdq, q_cluster, qcount);
  assign2_kernel<<<MROWS / 4, 256, 0, stream>>>(key,   Wck, bdk, k_cluster, kcount);

  scan_kernel<<<1, 64, 0, stream>>>(qcount, kcount, qoff, koff);
  scatter_kernel<<<(2 * MROWS) / 256, 256, 0, stream>>>(q_cluster, k_cluster, qoff, koff,
                                                        qfill, kfill, qlist, klist);
  attn_bucket<<<dim3(NC, NH, NB), 256, 0, stream>>>(Qb, Kb, Vb, qcount, qoff, qlist,
                                                    kcount, koff, klist, ctx);
  gemm_bt_mfma<1><<<gg, 256, 0, stream>>>(ctx, Wo, bo, proj, nullptr);
  ln_kernel<<<MROWS, 256, 0, stream>>>(proj, query, gamma, beta, out);
}